// Round 1
// baseline (2001.750 us; speedup 1.0000x reference)
//
#include <hip/hip_runtime.h>

// MHA forward: B=2, S=2048, C=1024, H=16, D=64
// Round 1: all-fp32 correctness baseline.
//   d_out = [ out: B*S*C floats | attn: B*H*S*S floats ]
//   d_ws  = [ Qh | Kh | Vh : each B*H*S*D (split-head) | Oh : B*S*C (merged) ] = 64 MB

#define B_  2
#define S_  2048
#define C_  1024
#define H_  16
#define D_  64
#define BS_ (B_ * S_)   // 4096

// ---------------------------------------------------------------------------
// proj_gemm: [4096,1024] @ [1024,1024] + bias
//   mode 0: write split-head layout out[((b*H+h)*S + s)*D + d]
//   mode 1: write row-major out[row*C + col]
// 64x64 tile, 256 threads, 4x4 register blocking, K-tile 16.
// ---------------------------------------------------------------------------
__global__ __launch_bounds__(256) void proj_gemm(
    const float* __restrict__ X, const float* __restrict__ W,
    const float* __restrict__ bias, float* __restrict__ out, int mode)
{
  __shared__ float As[16][68];   // As[k][row]  (A staged transposed)
  __shared__ float Bs[16][68];   // Bs[k][col]

  const int tid = threadIdx.x;
  const int tx  = tid & 15;      // 0..15 -> col group
  const int ty  = tid >> 4;      // 0..15 -> row group
  const int r0  = blockIdx.x * 64;
  const int c0  = blockIdx.y * 64;

  // staging indices
  const int ar = tid >> 2;           // 0..63 row within A tile
  const int ak = (tid & 3) << 2;     // 0,4,8,12 k offset
  const int bk = tid >> 4;           // 0..15 k row of B tile
  const int bc = (tid & 15) << 2;    // 0..60 col offset

  float acc[4][4] = {};

  for (int kt = 0; kt < C_; kt += 16) {
    float4 av = *(const float4*)&X[(size_t)(r0 + ar) * C_ + kt + ak];
    float4 bv = *(const float4*)&W[(size_t)(kt + bk) * C_ + c0 + bc];
    __syncthreads();   // previous iteration's reads complete
    As[ak + 0][ar] = av.x;
    As[ak + 1][ar] = av.y;
    As[ak + 2][ar] = av.z;
    As[ak + 3][ar] = av.w;
    *(float4*)&Bs[bk][bc] = bv;
    __syncthreads();
#pragma unroll
    for (int k = 0; k < 16; k++) {
      float4 a = *(const float4*)&As[k][ty << 2];
      float4 b = *(const float4*)&Bs[k][tx << 2];
      acc[0][0] += a.x * b.x; acc[0][1] += a.x * b.y; acc[0][2] += a.x * b.z; acc[0][3] += a.x * b.w;
      acc[1][0] += a.y * b.x; acc[1][1] += a.y * b.y; acc[1][2] += a.y * b.z; acc[1][3] += a.y * b.w;
      acc[2][0] += a.z * b.x; acc[2][1] += a.z * b.y; acc[2][2] += a.z * b.z; acc[2][3] += a.z * b.w;
      acc[3][0] += a.w * b.x; acc[3][1] += a.w * b.y; acc[3][2] += a.w * b.z; acc[3][3] += a.w * b.w;
    }
  }

  const int col = c0 + (tx << 2);
  const float b0 = bias[col + 0], b1 = bias[col + 1], b2 = bias[col + 2], b3 = bias[col + 3];
#pragma unroll
  for (int i = 0; i < 4; i++) {
    const int row = r0 + (ty << 2) + i;
    float4 v;
    v.x = acc[i][0] + b0;
    v.y = acc[i][1] + b1;
    v.z = acc[i][2] + b2;
    v.w = acc[i][3] + b3;
    if (mode == 0) {
      const int b = row >> 11;           // row / S
      const int s = row & (S_ - 1);
      const int h = col >> 6;            // col / D  (tile never crosses a head: c0 % 64 == 0)
      const int d = col & (D_ - 1);
      *(float4*)&out[(((size_t)(b * H_ + h)) * S_ + s) * D_ + d] = v;
    } else {
      *(float4*)&out[(size_t)row * C_ + col] = v;
    }
  }
}

// ---------------------------------------------------------------------------
// scores_kernel: per (b,h): attn_raw = (Qh @ Kh^T) * 1/sqrt(D)
// Qh,Kh: [BH, S, 64]. One block = 64x64 output tile, K=64 staged once.
// ---------------------------------------------------------------------------
__global__ __launch_bounds__(256) void scores_kernel(
    const float* __restrict__ Qh, const float* __restrict__ Kh,
    float* __restrict__ attn)
{
  __shared__ float Qs[64][68];   // Qs[k][i]
  __shared__ float Ks[64][68];   // Ks[k][j]

  const int tid = threadIdx.x;
  const int tx  = tid & 15;
  const int ty  = tid >> 4;
  const int bh  = blockIdx.z;
  const int i0  = blockIdx.x * 64;
  const int j0  = blockIdx.y * 64;

  const float* Q = Qh + (size_t)bh * S_ * D_;
  const float* K = Kh + (size_t)bh * S_ * D_;
  float* A = attn + (size_t)bh * S_ * S_;

  const int r = tid >> 2;                 // 0..63 row within tile
#pragma unroll
  for (int u = 0; u < 4; u++) {
    const int k = ((tid & 3) << 2) + (u << 4);   // coalesced 64B across 4 threads
    float4 qv = *(const float4*)&Q[(size_t)(i0 + r) * D_ + k];
    Qs[k + 0][r] = qv.x; Qs[k + 1][r] = qv.y; Qs[k + 2][r] = qv.z; Qs[k + 3][r] = qv.w;
    float4 kv = *(const float4*)&K[(size_t)(j0 + r) * D_ + k];
    Ks[k + 0][r] = kv.x; Ks[k + 1][r] = kv.y; Ks[k + 2][r] = kv.z; Ks[k + 3][r] = kv.w;
  }
  __syncthreads();

  float acc[4][4] = {};
#pragma unroll 8
  for (int k = 0; k < 64; k++) {
    float4 a = *(const float4*)&Qs[k][ty << 2];
    float4 b = *(const float4*)&Ks[k][tx << 2];
    acc[0][0] += a.x * b.x; acc[0][1] += a.x * b.y; acc[0][2] += a.x * b.z; acc[0][3] += a.x * b.w;
    acc[1][0] += a.y * b.x; acc[1][1] += a.y * b.y; acc[1][2] += a.y * b.z; acc[1][3] += a.y * b.w;
    acc[2][0] += a.z * b.x; acc[2][1] += a.z * b.y; acc[2][2] += a.z * b.z; acc[2][3] += a.z * b.w;
    acc[3][0] += a.w * b.x; acc[3][1] += a.w * b.y; acc[3][2] += a.w * b.z; acc[3][3] += a.w * b.w;
  }

  const float sc = 0.125f;   // 1/sqrt(64)
#pragma unroll
  for (int i = 0; i < 4; i++) {
    const int grow = i0 + (ty << 2) + i;
    float4 v;
    v.x = acc[i][0] * sc; v.y = acc[i][1] * sc; v.z = acc[i][2] * sc; v.w = acc[i][3] * sc;
    *(float4*)&A[(size_t)grow * S_ + j0 + (tx << 2)] = v;
  }
}

// ---------------------------------------------------------------------------
// softmax_kernel: in-place row softmax over 2048 columns. One block per row.
// ---------------------------------------------------------------------------
__global__ __launch_bounds__(256) void softmax_kernel(float* __restrict__ attn)
{
  float* p = attn + (size_t)blockIdx.x * S_;
  const int t = threadIdx.x;

  float4 x0 = ((const float4*)p)[t];
  float4 x1 = ((const float4*)p)[t + 256];

  float m = fmaxf(fmaxf(fmaxf(x0.x, x0.y), fmaxf(x0.z, x0.w)),
                  fmaxf(fmaxf(x1.x, x1.y), fmaxf(x1.z, x1.w)));
#pragma unroll
  for (int o = 32; o >= 1; o >>= 1) m = fmaxf(m, __shfl_xor(m, o));

  __shared__ float sm[4];
  __shared__ float ss[4];
  const int lane = t & 63, wid = t >> 6;
  if (lane == 0) sm[wid] = m;
  __syncthreads();
  m = fmaxf(fmaxf(sm[0], sm[1]), fmaxf(sm[2], sm[3]));

  x0.x = __expf(x0.x - m); x0.y = __expf(x0.y - m);
  x0.z = __expf(x0.z - m); x0.w = __expf(x0.w - m);
  x1.x = __expf(x1.x - m); x1.y = __expf(x1.y - m);
  x1.z = __expf(x1.z - m); x1.w = __expf(x1.w - m);

  float s = x0.x + x0.y + x0.z + x0.w + x1.x + x1.y + x1.z + x1.w;
#pragma unroll
  for (int o = 32; o >= 1; o >>= 1) s += __shfl_xor(s, o);
  if (lane == 0) ss[wid] = s;
  __syncthreads();
  s = ss[0] + ss[1] + ss[2] + ss[3];

  const float r = 1.0f / s;
  x0.x *= r; x0.y *= r; x0.z *= r; x0.w *= r;
  x1.x *= r; x1.y *= r; x1.z *= r; x1.w *= r;
  ((float4*)p)[t]       = x0;
  ((float4*)p)[t + 256] = x1;
}

// ---------------------------------------------------------------------------
// pv_kernel: per (b,h): Oh = attn @ Vh.  M=2048, N=64, K=2048.
// Block = 64 rows x 64 dims (full D), K-tiles of 64. Writes merged-head [B,S,C].
// ---------------------------------------------------------------------------
__global__ __launch_bounds__(256) void pv_kernel(
    const float* __restrict__ attn, const float* __restrict__ Vh,
    float* __restrict__ Oh)
{
  __shared__ float As[64][68];   // As[j][i]  (attn tile transposed)
  __shared__ float Bs[64][68];   // Bs[j][d]

  const int tid = threadIdx.x;
  const int tx  = tid & 15;
  const int ty  = tid >> 4;
  const int bh  = blockIdx.z;
  const int b   = bh >> 4;       // bh / H
  const int h   = bh & (H_ - 1);
  const int i0  = blockIdx.x * 64;

  const float* A = attn + (size_t)bh * S_ * S_;
  const float* V = Vh + (size_t)bh * S_ * D_;

  const int r = tid >> 2;        // 0..63
  float acc[4][4] = {};

  for (int j0 = 0; j0 < S_; j0 += 64) {
    float4 a_ld[4], b_ld[4];
#pragma unroll
    for (int u = 0; u < 4; u++) {
      const int c = ((tid & 3) << 2) + (u << 4);
      a_ld[u] = *(const float4*)&A[(size_t)(i0 + r) * S_ + j0 + c];
      b_ld[u] = *(const float4*)&V[(size_t)(j0 + r) * D_ + c];
    }
    __syncthreads();   // previous iteration's compute reads complete
#pragma unroll
    for (int u = 0; u < 4; u++) {
      const int c = ((tid & 3) << 2) + (u << 4);
      As[c + 0][r] = a_ld[u].x; As[c + 1][r] = a_ld[u].y;
      As[c + 2][r] = a_ld[u].z; As[c + 3][r] = a_ld[u].w;
      *(float4*)&Bs[r][c] = b_ld[u];
    }
    __syncthreads();
#pragma unroll 8
    for (int j = 0; j < 64; j++) {
      float4 a = *(const float4*)&As[j][ty << 2];
      float4 bb = *(const float4*)&Bs[j][tx << 2];
      acc[0][0] += a.x * bb.x; acc[0][1] += a.x * bb.y; acc[0][2] += a.x * bb.z; acc[0][3] += a.x * bb.w;
      acc[1][0] += a.y * bb.x; acc[1][1] += a.y * bb.y; acc[1][2] += a.y * bb.z; acc[1][3] += a.y * bb.w;
      acc[2][0] += a.z * bb.x; acc[2][1] += a.z * bb.y; acc[2][2] += a.z * bb.z; acc[2][3] += a.z * bb.w;
      acc[3][0] += a.w * bb.x; acc[3][1] += a.w * bb.y; acc[3][2] += a.w * bb.z; acc[3][3] += a.w * bb.w;
    }
  }

#pragma unroll
  for (int i = 0; i < 4; i++) {
    const int srow = i0 + (ty << 2) + i;
    float4 v;
    v.x = acc[i][0]; v.y = acc[i][1]; v.z = acc[i][2]; v.w = acc[i][3];
    *(float4*)&Oh[((size_t)b * S_ + srow) * C_ + h * D_ + (tx << 2)] = v;
  }
}

// ---------------------------------------------------------------------------
extern "C" void kernel_launch(void* const* d_in, const int* in_sizes, int n_in,
                              void* d_out, int out_size, void* d_ws, size_t ws_size,
                              hipStream_t stream)
{
  (void)in_sizes; (void)n_in; (void)out_size; (void)ws_size;

  const float* q  = (const float*)d_in[0];
  const float* k  = (const float*)d_in[1];
  const float* v  = (const float*)d_in[2];
  const float* wq = (const float*)d_in[3];
  const float* bq = (const float*)d_in[4];
  const float* wk = (const float*)d_in[5];
  const float* bk = (const float*)d_in[6];
  const float* wv = (const float*)d_in[7];
  const float* bv = (const float*)d_in[8];
  const float* wo = (const float*)d_in[9];
  const float* bo = (const float*)d_in[10];

  float* out  = (float*)d_out;
  float* attn = out + (size_t)BS_ * C_;          // 4,194,304 floats in

  float* ws = (float*)d_ws;
  float* Qh = ws;                                 // [B,H,S,D]
  float* Kh = Qh + (size_t)BS_ * C_;
  float* Vh = Kh + (size_t)BS_ * C_;
  float* Oh = Vh + (size_t)BS_ * C_;              // [B,S,C]  (total 64 MB)

  dim3 gProj(BS_ / 64, C_ / 64, 1);
  proj_gemm<<<gProj, 256, 0, stream>>>(q, wq, bq, Qh, 0);
  proj_gemm<<<gProj, 256, 0, stream>>>(k, wk, bk, Kh, 0);
  proj_gemm<<<gProj, 256, 0, stream>>>(v, wv, bv, Vh, 0);

  dim3 gSc(S_ / 64, S_ / 64, B_ * H_);
  scores_kernel<<<gSc, 256, 0, stream>>>(Qh, Kh, attn);

  softmax_kernel<<<dim3(B_ * H_ * S_), 256, 0, stream>>>(attn);

  dim3 gPv(S_ / 64, 1, B_ * H_);
  pv_kernel<<<gPv, 256, 0, stream>>>(attn, Vh, Oh);

  proj_gemm<<<gProj, 256, 0, stream>>>(Oh, wo, bo, out, 1);
}

// Round 2
// 1196.488 us; speedup vs baseline: 1.6730x; 1.6730x over previous
//
#include <hip/hip_runtime.h>

// MHA forward: B=2, S=2048, C=1024, H=16, D=64
// Round 2: split-bf16 (hi+lo) MFMA everywhere; fused exp-scores + normalize-in-PV.
//
// d_out = [ out: 4096*1024 f32 | attn: 32*2048*2048 f32 ]
//   out region is reused as x-split scratch (XS) until the final projection.
// d_ws  = [ QhHi QhLo KhHi KhLo VtHi VtLo : 6 x 4.19M bf16 | WtHi WtLo : 2 x 1M bf16 | rowsum: 65536 f32 ]  ~= 55 MB

#define S_  2048
#define C_  1024
#define H_  16
#define D_  64
#define BS_ 4096            // B*S
#define BH_ 32              // B*H

typedef unsigned short ushort_t;
typedef __attribute__((ext_vector_type(8))) short short8;
typedef __attribute__((ext_vector_type(4))) float floatx4;

#define GLDS16(gp, lp) __builtin_amdgcn_global_load_lds( \
    (__attribute__((address_space(1))) void*)(gp), \
    (__attribute__((address_space(3))) void*)(lp), 16, 0, 0)

#define MFMA16(a, b, c) __builtin_amdgcn_mfma_f32_16x16x32_bf16((a), (b), (c), 0, 0, 0)

__device__ __forceinline__ ushort_t f2bf(float x) {
  union { float f; unsigned u; } v; v.f = x;
  unsigned r = v.u + 0x7fffu + ((v.u >> 16) & 1u);   // round-to-nearest-even
  return (ushort_t)(r >> 16);
}
__device__ __forceinline__ float bf2f(ushort_t h) {
  union { unsigned u; float f; } v; v.u = ((unsigned)h) << 16; return v.f;
}

// ---------------------------------------------------------------------------
// split_plain: fp32[n4*4] -> hi/lo bf16 planes. One float4 per thread.
// ---------------------------------------------------------------------------
__global__ __launch_bounds__(256) void split_plain(
    const float* __restrict__ in, ushort_t* __restrict__ hi, ushort_t* __restrict__ lo)
{
  const int i = blockIdx.x * 256 + threadIdx.x;
  float4 v = ((const float4*)in)[i];
  ushort4 h, l;
  h.x = f2bf(v.x); l.x = f2bf(v.x - bf2f(h.x));
  h.y = f2bf(v.y); l.y = f2bf(v.y - bf2f(h.y));
  h.z = f2bf(v.z); l.z = f2bf(v.z - bf2f(h.z));
  h.w = f2bf(v.w); l.w = f2bf(v.w - bf2f(h.w));
  ((ushort4*)hi)[i] = h;
  ((ushort4*)lo)[i] = l;
}

// ---------------------------------------------------------------------------
// split_T: W[1024][1024] fp32 -> Wt hi/lo bf16 [n][k] (transposed).
// 64x64 tiles via LDS.
// ---------------------------------------------------------------------------
__global__ __launch_bounds__(256) void split_T(
    const float* __restrict__ W, ushort_t* __restrict__ THi, ushort_t* __restrict__ TLo)
{
  __shared__ float t[64][65];
  const int k0 = blockIdx.x * 64, n0 = blockIdx.y * 64;
  const int tid = threadIdx.x;
  const int r = tid >> 4, c4 = (tid & 15) * 4;
#pragma unroll
  for (int p = 0; p < 4; ++p) {
    float4 v = *(const float4*)&W[(size_t)(k0 + p * 16 + r) * C_ + n0 + c4];
    t[p * 16 + r][c4 + 0] = v.x;
    t[p * 16 + r][c4 + 1] = v.y;
    t[p * 16 + r][c4 + 2] = v.z;
    t[p * 16 + r][c4 + 3] = v.w;
  }
  __syncthreads();
  const int n = tid >> 2, kc = (tid & 3) * 16;
#pragma unroll
  for (int j = 0; j < 16; ++j) {
    float x = t[kc + j][n];
    ushort_t h = f2bf(x);
    const size_t idx = (size_t)(n0 + n) * C_ + k0 + kc + j;
    THi[idx] = h;
    TLo[idx] = f2bf(x - bf2f(h));
  }
}

// ---------------------------------------------------------------------------
// gemm_proj: C[4096,1024] = A[4096,1024] @ Bt[1024,1024]^T + bias, split-bf16.
// Tile 128(M) x 64(N), BK=32, 256 thr = 4 waves, wave quadrant 64x32.
//   mode 0: write split-head split-bf16  Q/K [bh][s][d]
//   mode 1: write transposed split-bf16  Vt  [bh][d][s]
//   mode 2: write fp32 row-major out
// ---------------------------------------------------------------------------
__global__ __launch_bounds__(256) void gemm_proj(
    const ushort_t* __restrict__ Ahi, const ushort_t* __restrict__ Alo,
    const ushort_t* __restrict__ Bhi, const ushort_t* __restrict__ Blo,
    const float* __restrict__ bias,
    ushort_t* __restrict__ OHi, ushort_t* __restrict__ OLo,
    float* __restrict__ OF, int mode)
{
  __shared__ ushort_t sA[2][128 * 32];
  __shared__ ushort_t sB[2][64 * 32];

  const int tid = threadIdx.x;
  const int wv = tid >> 6, ln = tid & 63;
  const int lq = ln >> 4, lr = ln & 15;
  const int wr = wv >> 1, wc = wv & 1;
  const int r0 = blockIdx.x * 128, c0 = blockIdx.y * 64;

  const int sar = wv * 32 + (ln >> 2);     // A staging row (chunk 0)
  const int sbr = wv * 16 + (ln >> 2);     // B staging row
  const int skc = (ln & 3) * 8;            // staging k offset (bf16 elems)

  floatx4 acc[4][2];
#pragma unroll
  for (int m = 0; m < 4; ++m)
#pragma unroll
    for (int n = 0; n < 2; ++n) acc[m][n] = (floatx4){0.f, 0.f, 0.f, 0.f};

  for (int kt = 0; kt < 1024; kt += 32) {
    __syncthreads();
#pragma unroll
    for (int c = 0; c < 2; ++c) {
      const int row = sar + c * 16;
      GLDS16(&Ahi[(size_t)(r0 + row) * 1024 + kt + skc], &sA[0][(wv * 32 + c * 16) * 32]);
      GLDS16(&Alo[(size_t)(r0 + row) * 1024 + kt + skc], &sA[1][(wv * 32 + c * 16) * 32]);
    }
    GLDS16(&Bhi[(size_t)(c0 + sbr) * 1024 + kt + skc], &sB[0][(wv * 16) * 32]);
    GLDS16(&Blo[(size_t)(c0 + sbr) * 1024 + kt + skc], &sB[1][(wv * 16) * 32]);
    __syncthreads();

    short8 af[4][2], bf[2][2];
#pragma unroll
    for (int t = 0; t < 4; ++t) {
      af[t][0] = *(const short8*)&sA[0][(wr * 64 + t * 16 + lr) * 32 + lq * 8];
      af[t][1] = *(const short8*)&sA[1][(wr * 64 + t * 16 + lr) * 32 + lq * 8];
    }
#pragma unroll
    for (int t = 0; t < 2; ++t) {
      bf[t][0] = *(const short8*)&sB[0][(wc * 32 + t * 16 + lr) * 32 + lq * 8];
      bf[t][1] = *(const short8*)&sB[1][(wc * 32 + t * 16 + lr) * 32 + lq * 8];
    }
#pragma unroll
    for (int m = 0; m < 4; ++m)
#pragma unroll
      for (int n = 0; n < 2; ++n) {
        acc[m][n] = MFMA16(af[m][1], bf[n][0], acc[m][n]);   // lo*hi
        acc[m][n] = MFMA16(af[m][0], bf[n][1], acc[m][n]);   // hi*lo
        acc[m][n] = MFMA16(af[m][0], bf[n][0], acc[m][n]);   // hi*hi
      }
  }

#pragma unroll
  for (int m = 0; m < 4; ++m) {
    const int grb = r0 + wr * 64 + m * 16 + lq * 4;
#pragma unroll
    for (int n = 0; n < 2; ++n) {
      const int gc = c0 + wc * 32 + n * 16 + lr;
      const float bs = bias[gc];
      if (mode == 2) {
#pragma unroll
        for (int r = 0; r < 4; ++r)
          OF[(size_t)(grb + r) * C_ + gc] = acc[m][n][r] + bs;
      } else if (mode == 0) {
        const int h = gc >> 6, d = gc & 63;
#pragma unroll
        for (int r = 0; r < 4; ++r) {
          const int gr = grb + r;
          const int b = gr >> 11, s = gr & (S_ - 1);
          const size_t idx = ((size_t)(b * H_ + h) * S_ + s) * D_ + d;
          float x = acc[m][n][r] + bs;
          ushort_t hx = f2bf(x);
          OHi[idx] = hx;
          OLo[idx] = f2bf(x - bf2f(hx));
        }
      } else {  // mode 1: Vt [bh][d][s], 4 regs = 4 consecutive s
        const int h = gc >> 6, d = gc & 63;
        const int b = grb >> 11, s = grb & (S_ - 1);
        const size_t idx = ((size_t)(b * H_ + h) * D_ + d) * S_ + s;
        ushort4 hv, lv;
        float x0 = acc[m][n][0] + bs, x1 = acc[m][n][1] + bs;
        float x2 = acc[m][n][2] + bs, x3 = acc[m][n][3] + bs;
        hv.x = f2bf(x0); lv.x = f2bf(x0 - bf2f(hv.x));
        hv.y = f2bf(x1); lv.y = f2bf(x1 - bf2f(hv.y));
        hv.z = f2bf(x2); lv.z = f2bf(x2 - bf2f(hv.z));
        hv.w = f2bf(x3); lv.w = f2bf(x3 - bf2f(hv.w));
        *(ushort4*)&OHi[idx] = hv;
        *(ushort4*)&OLo[idx] = lv;
      }
    }
  }
}

// ---------------------------------------------------------------------------
// scores_exp: per bh, E = exp(Q@K^T * 0.125) (unnormalized), rowsum += partials.
// Tile 128x128, K=64 (2 steps of 32).
// ---------------------------------------------------------------------------
__global__ __launch_bounds__(256) void scores_exp(
    const ushort_t* __restrict__ QHi, const ushort_t* __restrict__ QLo,
    const ushort_t* __restrict__ KHi, const ushort_t* __restrict__ KLo,
    float* __restrict__ E, float* __restrict__ rowsum)
{
  __shared__ ushort_t sA[2][128 * 32];
  __shared__ ushort_t sB[2][128 * 32];

  const int tid = threadIdx.x;
  const int wv = tid >> 6, ln = tid & 63;
  const int lq = ln >> 4, lr = ln & 15;
  const int wr = wv >> 1, wc = wv & 1;
  const int bh = blockIdx.z;
  const int i0 = blockIdx.x * 128, j0 = blockIdx.y * 128;

  const ushort_t* Qh = QHi + (size_t)bh * S_ * D_;
  const ushort_t* Ql = QLo + (size_t)bh * S_ * D_;
  const ushort_t* Kh = KHi + (size_t)bh * S_ * D_;
  const ushort_t* Kl = KLo + (size_t)bh * S_ * D_;

  const int sar = wv * 32 + (ln >> 2);
  const int skc = (ln & 3) * 8;

  floatx4 acc[4][4];
#pragma unroll
  for (int m = 0; m < 4; ++m)
#pragma unroll
    for (int n = 0; n < 4; ++n) acc[m][n] = (floatx4){0.f, 0.f, 0.f, 0.f};

#pragma unroll
  for (int kt = 0; kt < 64; kt += 32) {
    __syncthreads();
#pragma unroll
    for (int c = 0; c < 2; ++c) {
      const int row = sar + c * 16;
      GLDS16(&Qh[(size_t)(i0 + row) * D_ + kt + skc], &sA[0][(wv * 32 + c * 16) * 32]);
      GLDS16(&Ql[(size_t)(i0 + row) * D_ + kt + skc], &sA[1][(wv * 32 + c * 16) * 32]);
      GLDS16(&Kh[(size_t)(j0 + row) * D_ + kt + skc], &sB[0][(wv * 32 + c * 16) * 32]);
      GLDS16(&Kl[(size_t)(j0 + row) * D_ + kt + skc], &sB[1][(wv * 32 + c * 16) * 32]);
    }
    __syncthreads();

    short8 af[4][2], bf[4][2];
#pragma unroll
    for (int t = 0; t < 4; ++t) {
      af[t][0] = *(const short8*)&sA[0][(wr * 64 + t * 16 + lr) * 32 + lq * 8];
      af[t][1] = *(const short8*)&sA[1][(wr * 64 + t * 16 + lr) * 32 + lq * 8];
      bf[t][0] = *(const short8*)&sB[0][(wc * 64 + t * 16 + lr) * 32 + lq * 8];
      bf[t][1] = *(const short8*)&sB[1][(wc * 64 + t * 16 + lr) * 32 + lq * 8];
    }
#pragma unroll
    for (int m = 0; m < 4; ++m)
#pragma unroll
      for (int n = 0; n < 4; ++n) {
        acc[m][n] = MFMA16(af[m][1], bf[n][0], acc[m][n]);
        acc[m][n] = MFMA16(af[m][0], bf[n][1], acc[m][n]);
        acc[m][n] = MFMA16(af[m][0], bf[n][0], acc[m][n]);
      }
  }

  float* Eb = E + (size_t)bh * S_ * S_;
  const float cexp = 0.18033688011112042f;   // 0.125 * log2(e)
#pragma unroll
  for (int m = 0; m < 4; ++m) {
    const int grb = i0 + wr * 64 + m * 16 + lq * 4;
    float ps[4] = {0.f, 0.f, 0.f, 0.f};
#pragma unroll
    for (int n = 0; n < 4; ++n) {
      const int gc = j0 + wc * 64 + n * 16 + lr;
#pragma unroll
      for (int r = 0; r < 4; ++r) {
        float e = exp2f(acc[m][n][r] * cexp);
        Eb[(size_t)(grb + r) * S_ + gc] = e;
        ps[r] += e;
      }
    }
#pragma unroll
    for (int r = 0; r < 4; ++r) {
      float s = ps[r];
      s += __shfl_xor(s, 1);
      s += __shfl_xor(s, 2);
      s += __shfl_xor(s, 4);
      s += __shfl_xor(s, 8);
      if (lr == 0) atomicAdd(&rowsum[bh * S_ + grb + r], s);
    }
  }
}

// ---------------------------------------------------------------------------
// pv_attn: per bh: O = (E @ Vt^T) / rowsum ; also writes attn = E/rowsum
// in-place during the streaming K-loop. Tile 128(M) x 64(D), BK=32.
// Oh written as split-bf16 merged-head [4096][1024].
// ---------------------------------------------------------------------------
__global__ __launch_bounds__(256) void pv_attn(
    float* __restrict__ E,
    const ushort_t* __restrict__ VHi, const ushort_t* __restrict__ VLo,
    const float* __restrict__ rowsum,
    ushort_t* __restrict__ OHi, ushort_t* __restrict__ OLo)
{
  __shared__ ushort_t sA[2][128 * 32];
  __shared__ ushort_t sB[2][64 * 32];

  const int tid = threadIdx.x;
  const int wv = tid >> 6, ln = tid & 63;
  const int lq = ln >> 4, lr = ln & 15;
  const int bh = blockIdx.z, b = bh >> 4, h = bh & (H_ - 1);
  const int i0 = blockIdx.x * 128;

  float* Eb = E + (size_t)bh * S_ * S_;
  const ushort_t* Vh = VHi + (size_t)bh * D_ * S_;
  const ushort_t* Vl = VLo + (size_t)bh * D_ * S_;

  const int ar = tid >> 3;            // 0..31  (A staging row within 32-row chunk)
  const int ac = (tid & 7) * 4;       // 0..28  (A staging col, float4)
  float rinv_s[4];
#pragma unroll
  for (int u = 0; u < 4; ++u)
    rinv_s[u] = 1.0f / rowsum[bh * S_ + i0 + u * 32 + ar];

  const int sbr = wv * 16 + (ln >> 2);
  const int skc = (ln & 3) * 8;

  floatx4 acc[2][4];
#pragma unroll
  for (int m = 0; m < 2; ++m)
#pragma unroll
    for (int n = 0; n < 4; ++n) acc[m][n] = (floatx4){0.f, 0.f, 0.f, 0.f};

  for (int kt = 0; kt < S_; kt += 32) {
    __syncthreads();
    GLDS16(&Vh[(size_t)sbr * S_ + kt + skc], &sB[0][(wv * 16) * 32]);
    GLDS16(&Vl[(size_t)sbr * S_ + kt + skc], &sB[1][(wv * 16) * 32]);
#pragma unroll
    for (int u = 0; u < 4; ++u) {
      const int row = u * 32 + ar;
      float4 ev = *(const float4*)&Eb[(size_t)(i0 + row) * S_ + kt + ac];
      float4 nv;
      nv.x = ev.x * rinv_s[u]; nv.y = ev.y * rinv_s[u];
      nv.z = ev.z * rinv_s[u]; nv.w = ev.w * rinv_s[u];
      *(float4*)&Eb[(size_t)(i0 + row) * S_ + kt + ac] = nv;   // normalized attn out
      ushort4 h4, l4;
      h4.x = f2bf(ev.x); l4.x = f2bf(ev.x - bf2f(h4.x));
      h4.y = f2bf(ev.y); l4.y = f2bf(ev.y - bf2f(h4.y));
      h4.z = f2bf(ev.z); l4.z = f2bf(ev.z - bf2f(h4.z));
      h4.w = f2bf(ev.w); l4.w = f2bf(ev.w - bf2f(h4.w));
      *(ushort4*)&sA[0][row * 32 + ac] = h4;
      *(ushort4*)&sA[1][row * 32 + ac] = l4;
    }
    __syncthreads();

    short8 af[2][2], bf[4][2];
#pragma unroll
    for (int t = 0; t < 2; ++t) {
      af[t][0] = *(const short8*)&sA[0][(wv * 32 + t * 16 + lr) * 32 + lq * 8];
      af[t][1] = *(const short8*)&sA[1][(wv * 32 + t * 16 + lr) * 32 + lq * 8];
    }
#pragma unroll
    for (int t = 0; t < 4; ++t) {
      bf[t][0] = *(const short8*)&sB[0][(t * 16 + lr) * 32 + lq * 8];
      bf[t][1] = *(const short8*)&sB[1][(t * 16 + lr) * 32 + lq * 8];
    }
#pragma unroll
    for (int m = 0; m < 2; ++m)
#pragma unroll
      for (int n = 0; n < 4; ++n) {
        acc[m][n] = MFMA16(af[m][1], bf[n][0], acc[m][n]);
        acc[m][n] = MFMA16(af[m][0], bf[n][1], acc[m][n]);
        acc[m][n] = MFMA16(af[m][0], bf[n][0], acc[m][n]);
      }
  }

#pragma unroll
  for (int m = 0; m < 2; ++m) {
    const int rowb = wv * 32 + m * 16 + lq * 4;
#pragma unroll
    for (int r = 0; r < 4; ++r) {
      const float rv = 1.0f / rowsum[bh * S_ + i0 + rowb + r];
      const size_t orow = (size_t)(b * S_ + i0 + rowb + r) * C_ + h * D_;
#pragma unroll
      for (int n = 0; n < 4; ++n) {
        float x = acc[m][n][r] * rv;
        ushort_t hx = f2bf(x);
        OHi[orow + n * 16 + lr] = hx;
        OLo[orow + n * 16 + lr] = f2bf(x - bf2f(hx));
      }
    }
  }
}

// ---------------------------------------------------------------------------
extern "C" void kernel_launch(void* const* d_in, const int* in_sizes, int n_in,
                              void* d_out, int out_size, void* d_ws, size_t ws_size,
                              hipStream_t stream)
{
  (void)in_sizes; (void)n_in; (void)out_size; (void)ws_size;

  const float* q  = (const float*)d_in[0];
  const float* k  = (const float*)d_in[1];
  const float* v  = (const float*)d_in[2];
  const float* wq = (const float*)d_in[3];
  const float* bq = (const float*)d_in[4];
  const float* wk = (const float*)d_in[5];
  const float* bk = (const float*)d_in[6];
  const float* wv = (const float*)d_in[7];
  const float* bv = (const float*)d_in[8];
  const float* wo = (const float*)d_in[9];
  const float* bo = (const float*)d_in[10];

  const size_t NE = (size_t)BS_ * C_;          // 4,194,304

  float* outF = (float*)d_out;
  float* Ebuf = outF + NE;                      // attn region
  ushort_t* XSHi = (ushort_t*)d_out;            // x-split scratch lives in out region
  ushort_t* XSLo = XSHi + NE;                   // (exactly fills the 16.8 MB out area)

  ushort_t* ws16 = (ushort_t*)d_ws;
  ushort_t* QhHi = ws16;           ushort_t* QhLo = QhHi + NE;
  ushort_t* KhHi = QhLo + NE;      ushort_t* KhLo = KhHi + NE;
  ushort_t* VtHi = KhLo + NE;      ushort_t* VtLo = VtHi + NE;
  ushort_t* WtHi = VtLo + NE;      ushort_t* WtLo = WtHi + (size_t)C_ * C_;
  float* rowsum = (float*)(WtLo + (size_t)C_ * C_);

  const dim3 gS(NE / 4 / 256);          // split_plain grid
  const dim3 gT(16, 16);                // split_T grid
  const dim3 gP(BS_ / 128, C_ / 64);    // proj grid (32,16)
  const dim3 gSc(S_ / 128, S_ / 128, BH_);
  const dim3 gPv(S_ / 128, 1, BH_);

  // Q projection
  split_T<<<gT, 256, 0, stream>>>(wq, WtHi, WtLo);
  split_plain<<<gS, 256, 0, stream>>>(q, XSHi, XSLo);
  gemm_proj<<<gP, 256, 0, stream>>>(XSHi, XSLo, WtHi, WtLo, bq, QhHi, QhLo, nullptr, 0);
  // K projection
  split_T<<<gT, 256, 0, stream>>>(wk, WtHi, WtLo);
  split_plain<<<gS, 256, 0, stream>>>(k, XSHi, XSLo);
  gemm_proj<<<gP, 256, 0, stream>>>(XSHi, XSLo, WtHi, WtLo, bk, KhHi, KhLo, nullptr, 0);
  // V projection (transposed output)
  split_T<<<gT, 256, 0, stream>>>(wv, WtHi, WtLo);
  split_plain<<<gS, 256, 0, stream>>>(v, XSHi, XSLo);
  gemm_proj<<<gP, 256, 0, stream>>>(XSHi, XSLo, WtHi, WtLo, bv, VtHi, VtLo, nullptr, 1);

  // scores -> unnormalized exp + rowsums
  hipMemsetAsync(rowsum, 0, (size_t)BH_ * S_ * sizeof(float), stream);
  scores_exp<<<gSc, 256, 0, stream>>>(QhHi, QhLo, KhHi, KhLo, Ebuf, rowsum);

  // PV + in-place attn normalization; Oh reuses the Qh slot
  pv_attn<<<gPv, 256, 0, stream>>>(Ebuf, VtHi, VtLo, rowsum, QhHi, QhLo);

  // output projection
  split_T<<<gT, 256, 0, stream>>>(wo, WtHi, WtLo);
  gemm_proj<<<gP, 256, 0, stream>>>(QhHi, QhLo, WtHi, WtLo, bo, nullptr, nullptr, outF, 2);
}